// Round 9
// baseline (892.379 us; speedup 1.0000x reference)
//
#include <hip/hip_runtime.h>
#include <hip/hip_bf16.h>
#include <math.h>

// SharedLora on MI355X — round 9.
// r8 lesson: comp-in-VGPR thrashes (compiler picked 48 VGPR, rematerialized).
// r9: comp column forced into SGPRs via readfirstlane(c) + transposed compT
// (wave-uniform address -> s_load; zero VGPR cost). Block = 640 thr, 4 tiles,
// double-buffered LDS U (43 KB), async stage split (load t+1 to regs BEFORE
// computing tile t, ds_write after) -> HBM latency hidden in-block.
// KL: L6..L3 quads fused (PQ, L1/L2-hot re-read), L0-2 in k_klc.

#define NROI 256
#define NC 20
#define NFINAL 8000
#define NCUTS 500000
#define TB 256
#define NTILE 32           // 8000 / 256 = 31.25 -> tile 31 has 64 bins
#define TPB 4              // tiles per block
#define UROW (20 * TB)
#define BUFSZ (21 * TB)    // U rows + bias row (floats)

__global__ void k_init(const float* __restrict__ comp,
                       float* __restrict__ g2, float* __restrict__ compT,
                       float* __restrict__ kl)
{
    const int tid = threadIdx.x;
    if (tid == 0) kl[0] = (float)(-80076800.0 * 1.3244036413128371);
    for (int i = tid; i < 400; i += 256) {
        const int a = i / 20, b = i % 20;
        float s = 0.f;
#pragma unroll
        for (int c = 0; c < 20; c++) s += comp[a * 20 + c] * comp[b * 20 + c];
        // upper-triangular, off-diag doubled: q = sum_a x_a * sum_{b>=a} g2 x_b
        g2[i] = (b < a) ? 0.f : (b == a ? s : 2.f * s);
        compT[i] = comp[b * 20 + a];   // compT[c][a] = comp[a][c]
    }
}

__global__ __launch_bounds__(640, 5) void k_main(
    const float* __restrict__ compT, const float* __restrict__ g2,
    const float* __restrict__ wb0, const float* __restrict__ wd0,
    const float* __restrict__ wb1, const float* __restrict__ wd1,
    const float* __restrict__ wb2, const float* __restrict__ wd2,
    const float* __restrict__ wb3, const float* __restrict__ wd3,
    const float* __restrict__ wb4, const float* __restrict__ wd4,
    const float* __restrict__ wb5, const float* __restrict__ wd5,
    const float* __restrict__ wb6, const float* __restrict__ wd6,
    const int* __restrict__ regions_oi,
    __hip_bfloat16* __restrict__ w2,
    float* __restrict__ s_part, float* __restrict__ kl_out)
{
    __shared__ float U_sh[2][BUFSZ];    // 43,008 B
    __shared__ float klp[10];

    const int tid = threadIdx.x;
    const int wv = tid >> 6, lane = tid & 63;
    const int r = blockIdx.x & 255;     // same-region blocks land on one XCD
    const int oct = blockIdx.x >> 8;
    const int t0 = oct * TPB;
    const int r0 = regions_oi[r];

    const float* __restrict__ p6 = wd6 + (size_t)r0 * (20 * 8000);
    const float* __restrict__ p5 = wd5 + (size_t)r0 * (20 * 4000);
    const float* __restrict__ p4 = wd4 + (size_t)r0 * (20 * 2000);
    const float* __restrict__ p3 = wd3 + (size_t)r0 * (20 * 1000);
    const float* __restrict__ p2 = wd2 + (size_t)r0 * (20 * 400);
    const float* __restrict__ p1 = wd1 + (size_t)r0 * (20 * 200);
    const float* __restrict__ p0 = wd0 + (size_t)r0 * (20 * 40);
    const float* __restrict__ b6 = wb6 + (size_t)r0 * 8000;
    const float* __restrict__ b5 = wb5 + (size_t)r0 * 4000;
    const float* __restrict__ b4 = wb4 + (size_t)r0 * 2000;
    const float* __restrict__ b3 = wb3 + (size_t)r0 * 1000;
    const float* __restrict__ b2 = wb2 + (size_t)r0 * 400;
    const float* __restrict__ b1 = wb1 + (size_t)r0 * 200;
    const float* __restrict__ b0 = wb0 + (size_t)r0 * 40;

    // staging registers (held across the compute phase = T14 async split)
    float4 v6[2]; float2 v5[2];
    float s4[2], s3[2], s2r[2], s1r[2], s0r[2];
    float4 bv6; float2 bv5; float bs4, bs3, bs2, bs1, bs0;

    auto LOADF = [&](int tl) {
#pragma unroll
        for (int k = 0; k < 2; k++) {
            const int u = tid + 640 * k;            // 1280 U units
            const int a = u >> 6, jq = u & 63;
            const int j = (tl << 8) + 4 * jq;
            if (j < NFINAL) {
                v6[k] = *(const float4*)(p6 + (size_t)a * 8000 + j);
                v5[k] = *(const float2*)(p5 + a * 4000 + (j >> 1));
                s4[k] = p4[a * 2000 + (j >> 2)];
                s3[k] = p3[a * 1000 + (j >> 3)];
                s2r[k] = p2[a * 400 + j / 20];
                s1r[k] = p1[a * 200 + j / 40];
                s0r[k] = p0[a * 40 + j / 200];
            } else {
                v6[k] = make_float4(0.f, 0.f, 0.f, 0.f);
                v5[k] = make_float2(0.f, 0.f);
                s4[k] = s3[k] = s2r[k] = s1r[k] = s0r[k] = 0.f;
            }
        }
        if (tid < 64) {                             // 64 bias units
            const int j = (tl << 8) + 4 * tid;
            if (j < NFINAL) {
                bv6 = *(const float4*)(b6 + j);
                bv5 = *(const float2*)(b5 + (j >> 1));
                bs4 = b4[j >> 2]; bs3 = b3[j >> 3]; bs2 = b2[j / 20];
                bs1 = b1[j / 40]; bs0 = b0[j / 200];
            } else {
                bv6 = make_float4(0.f, 0.f, 0.f, 0.f);
                bv5 = make_float2(0.f, 0.f);
                bs4 = bs3 = bs2 = bs1 = bs0 = 0.f;
            }
        }
    };

    auto WRITEF = [&](int buf) {
#pragma unroll
        for (int k = 0; k < 2; k++) {
            const int u = tid + 640 * k;
            const int a = u >> 6, jq = u & 63;
            const float sc = s4[k] + s3[k] + s2r[k] + s1r[k] + s0r[k];
            const float c01 = sc + v5[k].x, c23 = sc + v5[k].y;
            float4 uu;
            uu.x = v6[k].x + c01; uu.y = v6[k].y + c01;
            uu.z = v6[k].z + c23; uu.w = v6[k].w + c23;
            *(float4*)(&U_sh[buf][a * TB + 4 * jq]) = uu;
        }
        if (tid < 64) {
            const float sc = bs4 + bs3 + bs2 + bs1 + bs0;
            const float c01 = sc + bv5.x, c23 = sc + bv5.y;
            float4 uu;
            uu.x = bv6.x + c01; uu.y = bv6.y + c01;
            uu.z = bv6.z + c23; uu.w = bv6.w + c23;
            *(float4*)(&U_sh[buf][UROW + 4 * tid]) = uu;
        }
    };

    auto PAF = [&](int buf, int tl) {
        const int j = (tl << 8) + 4 * lane;
        const bool ok = j < NFINAL;
        const float4 bi = *(const float4*)(&U_sh[buf][UROW + 4 * lane]);
#pragma unroll
        for (int p = 0; p < 2; p++) {
            const int c = __builtin_amdgcn_readfirstlane((wv << 1) | p);
            const float* __restrict__ cc = compT + c * 20;   // uniform -> s_load
            float4 acc = bi;
#pragma unroll
            for (int a = 0; a < 20; a++) {
                const float4 uu = *(const float4*)(&U_sh[buf][a * TB + 4 * lane]);
                const float f = cc[a];
                acc.x += f * uu.x; acc.y += f * uu.y;
                acc.z += f * uu.z; acc.w += f * uu.w;
            }
            float se = 0.f;
            if (ok) {
                union { __hip_bfloat162 h2[2]; uint2 u2; } pk;
                pk.h2[0] = __float22bfloat162_rn(make_float2(acc.x, acc.y));
                pk.h2[1] = __float22bfloat162_rn(make_float2(acc.z, acc.w));
                *(uint2*)(w2 + (size_t)(r * 20 + c) * 8000 + j) = pk.u2;
                // |w| small (~<4): unnormalized exp-sum safe in f32
                se = __expf(acc.x) + __expf(acc.y) + __expf(acc.z) + __expf(acc.w);
            }
#pragma unroll
            for (int off = 32; off > 0; off >>= 1) se += __shfl_down(se, off, 64);
            if (lane == 0) s_part[((size_t)r * NTILE + tl) * 20 + c] = se;
        }
    };

    float q = 0.f;
    auto PQF = [&](int tl) {
        const int base = tl << 8;
        const float* P; int K, col;
        if (tid < 256)      { P = p6; K = 8000; col = base + tid; }
        else if (tid < 384) { P = p5; K = 4000; col = (base >> 1) + (tid - 256); }
        else if (tid < 448) { P = p4; K = 2000; col = (base >> 2) + (tid - 384); }
        else if (tid < 480) { P = p3; K = 1000; col = (base >> 3) + (tid - 448); }
        else return;
        if (col >= K) return;
        float x[20];
#pragma unroll
        for (int a = 0; a < 20; a++) x[a] = P[(size_t)a * K + col];
#pragma unroll
        for (int a = 0; a < 20; a++) {
            float t = g2[a * 20 + a] * x[a];      // uniform offsets -> s_load
#pragma unroll
            for (int b = a + 1; b < 20; b++) t += g2[a * 20 + b] * x[b];
            q += x[a] * t;
        }
    };

    // ---- pipelined main loop: 1 barrier per tile ----
    LOADF(t0);
    WRITEF(0);
    __syncthreads();
#pragma unroll 1
    for (int t = 0; t < TPB; t++) {
        if (t < TPB - 1) LOADF(t0 + t + 1);   // issue next-tile loads early
        PAF(t & 1, t0 + t);                    // compute on current buffer
        PQF(t0 + t);                           // KL quads (cache-hot)
        if (t < TPB - 1) {
            WRITEF((t + 1) & 1);               // land prefetch in other buffer
            __syncthreads();
        }
    }

    // ---- KL reduction ----
#pragma unroll
    for (int off = 32; off > 0; off >>= 1) q += __shfl_down(q, off, 64);
    if (lane == 0) klp[wv] = q;
    __syncthreads();
    if (tid == 0) {
        float s = 0.f;
#pragma unroll
        for (int k = 0; k < 10; k++) s += klp[k];
        atomicAdd(kl_out, s * (-0.5f / 2.25f));
    }
}

// KL quads for levels 0..2 (40+200+400 = 640 cols per region)
__global__ __launch_bounds__(256, 2) void k_klc(
    const float* __restrict__ g2,
    const float* __restrict__ wd0, const float* __restrict__ wd1,
    const float* __restrict__ wd2,
    const int* __restrict__ regions_oi, float* __restrict__ kl_out)
{
    __shared__ float klp[4];
    const int tid = threadIdx.x;
    const int r0 = regions_oi[blockIdx.x];
    const float* __restrict__ p2 = wd2 + (size_t)r0 * (20 * 400);
    const float* __restrict__ p1 = wd1 + (size_t)r0 * (20 * 200);
    const float* __restrict__ p0 = wd0 + (size_t)r0 * (20 * 40);

    float q = 0.f;
#pragma unroll 1
    for (int it = 0; it < 3; it++) {
        const int u = it * 256 + tid;
        if (u >= 640) break;
        const float* P; int K, col;
        if (u < 400)      { P = p2; K = 400; col = u; }
        else if (u < 600) { P = p1; K = 200; col = u - 400; }
        else              { P = p0; K = 40;  col = u - 600; }
        float x[20];
#pragma unroll
        for (int a = 0; a < 20; a++) x[a] = P[a * K + col];
#pragma unroll
        for (int a = 0; a < 20; a++) {
            float t = g2[a * 20 + a] * x[a];
#pragma unroll
            for (int b = a + 1; b < 20; b++) t += g2[a * 20 + b] * x[b];
            q += x[a] * t;
        }
    }
#pragma unroll
    for (int off = 32; off > 0; off >>= 1) q += __shfl_down(q, off, 64);
    if ((tid & 63) == 0) klp[tid >> 6] = q;
    __syncthreads();
    if (tid == 0)
        atomicAdd(kl_out, (klp[0] + klp[1] + klp[2] + klp[3]) * (-0.5f / 2.25f));
}

__global__ void k_sub(const float* __restrict__ s_part, float* __restrict__ sub)
{
    const int i = blockIdx.x * 256 + threadIdx.x;
    if (i >= NROI * NC) return;
    const int r = i / 20, c = i % 20;
    float s = 0.f;
#pragma unroll 1
    for (int t = 0; t < NTILE; t++) s += s_part[(size_t)(r * NTILE + t) * 20 + c];
    sub[i] = logf(s) + 3.2188758248682006f;   // + log(25)
}

__global__ void k_gather(const int* __restrict__ lri, const int* __restrict__ lci,
                         const int* __restrict__ cli, const int* __restrict__ coords,
                         const __hip_bfloat16* __restrict__ w2,
                         const float* __restrict__ sub,
                         float* __restrict__ out)
{
    const int i = blockIdx.x * 256 + threadIdx.x;
    if (i >= NCUTS) return;
    const int r = lri[i];
    const int c = cli[lci[i]];
    int co = coords[i];
    co = co < 0 ? 0 : (co > 199999 ? 199999 : co);
    const int bin = co / 25;
    const int rc = r * 20 + c;
    out[i] = __bfloat162float(w2[(size_t)rc * 8000 + bin]) - sub[rc];
}

extern "C" void kernel_launch(void* const* d_in, const int* in_sizes, int n_in,
                              void* d_out, int out_size, void* d_ws, size_t ws_size,
                              hipStream_t stream)
{
    const float* comp = (const float*)d_in[0];
    const float* wb[7];
    const float* wd[7];
    if (in_sizes[2] == 400000) {
        for (int l = 0; l < 7; l++) { wb[l] = (const float*)d_in[1 + 2 * l]; wd[l] = (const float*)d_in[2 + 2 * l]; }
    } else {
        for (int l = 0; l < 7; l++) { wb[l] = (const float*)d_in[1 + l]; wd[l] = (const float*)d_in[8 + l]; }
    }
    const int* regions_oi = (const int*)d_in[15];
    const int* lri   = (const int*)d_in[16];
    const int* lci   = (const int*)d_in[17];
    const int* cli   = (const int*)d_in[18];
    const int* coords= (const int*)d_in[19];
    float* out = (float*)d_out;

    __hip_bfloat16* w2 = (__hip_bfloat16*)d_ws;                     // 81.92 MB
    float* s_part = (float*)(w2 + (size_t)NROI * NC * NFINAL);      // 8192*20 f32
    float* sub    = s_part + (size_t)NROI * NTILE * 20;             // 5120 f32
    float* g2buf  = sub + NROI * NC;                                // 400 f32
    float* compT  = g2buf + 400;                                    // 400 f32
    const size_t need = (size_t)NROI * NC * NFINAL * 2
                      + ((size_t)NROI * NTILE * 20 + NROI * NC + 800) * sizeof(float);
    if (ws_size < need) return;

    k_init<<<1, 256, 0, stream>>>(comp, g2buf, compT, out + NCUTS);
    k_main<<<NROI * NTILE / TPB, 640, 0, stream>>>(compT, g2buf,
        wb[0], wd[0], wb[1], wd[1], wb[2], wd[2], wb[3], wd[3],
        wb[4], wd[4], wb[5], wd[5], wb[6], wd[6],
        regions_oi, w2, s_part, out + NCUTS);
    k_klc<<<NROI, 256, 0, stream>>>(g2buf, wd[0], wd[1], wd[2],
        regions_oi, out + NCUTS);
    k_sub<<<(NROI * NC + 255) / 256, 256, 0, stream>>>(s_part, sub);
    k_gather<<<(NCUTS + 255) / 256, 256, 0, stream>>>(lri, lci, cli, coords,
        w2, sub, out);
}

// Round 10
// 196.529 us; speedup vs baseline: 4.5407x; 4.5407x over previous
//
#include <hip/hip_runtime.h>
#include <hip/hip_bf16.h>
#include <math.h>

// SharedLora on MI355X — round 10.
// Law from r1/r3/r6/r9: no cross-phase register staging, no tight VGPR bounds.
// r10 = r7/r8 structure with provably-uniform scalar operands:
//   - compT + readfirstlane(cluster-base) -> coefficients are s_loads folded
//     into v_fma(s,v,v); zero VGPR, zero in-loop VMEM.
//   - block 256 thr; wave = 5 clusters x 256-bin tile in 2 passes (3+2);
//     lane = one float4 bin-group. P0 stages level-summed U in LDS (21 KB).
//   - PQ: fused KL quads for L6..L3 (L2-hot re-read), g2 via s_load;
//     L0..L2 in k_klc. w stored bf16 (gather L3-resident).

#define NROI 256
#define NC 20
#define NFINAL 8000
#define NCUTS 500000
#define TB 256
#define NTILE 32           // tile 31 partial (64 bins)

__global__ void k_init(const float* __restrict__ comp,
                       float* __restrict__ g2, float* __restrict__ compT,
                       float* __restrict__ kl)
{
    const int tid = threadIdx.x;
    if (tid == 0) kl[0] = (float)(-80076800.0 * 1.3244036413128371);
    for (int i = tid; i < 400; i += 256) {
        const int a = i / 20, b = i % 20;
        float s = 0.f;
#pragma unroll
        for (int c = 0; c < 20; c++) s += comp[a * 20 + c] * comp[b * 20 + c];
        // upper-triangular, off-diag doubled: q = sum_a x_a * sum_{b>=a} g2 x_b
        g2[i] = (b < a) ? 0.f : (b == a ? s : 2.f * s);
        compT[i] = comp[b * 20 + a];   // compT[c*20+a] = comp[a*20+c]
    }
}

__global__ __launch_bounds__(256, 2) void k_main(
    const float* __restrict__ compT, const float* __restrict__ g2,
    const float* __restrict__ wb0, const float* __restrict__ wd0,
    const float* __restrict__ wb1, const float* __restrict__ wd1,
    const float* __restrict__ wb2, const float* __restrict__ wd2,
    const float* __restrict__ wb3, const float* __restrict__ wd3,
    const float* __restrict__ wb4, const float* __restrict__ wd4,
    const float* __restrict__ wb5, const float* __restrict__ wd5,
    const float* __restrict__ wb6, const float* __restrict__ wd6,
    const int* __restrict__ regions_oi,
    __hip_bfloat16* __restrict__ w2,
    float* __restrict__ s_part, float* __restrict__ kl_out)
{
    __shared__ float U_sh[20 * TB];    // 20 KiB
    __shared__ float bias_sh[TB];      // 1 KiB
    __shared__ float klp[4];

    const int tid = threadIdx.x;
    const int wv = tid >> 6, lane = tid & 63;
    const int r = blockIdx.x >> 5;
    const int tile = blockIdx.x & 31;
    const int base = tile << 8;
    const int r0 = regions_oi[r];

    const float* __restrict__ p6 = wd6 + (size_t)r0 * (20 * 8000);
    const float* __restrict__ p5 = wd5 + (size_t)r0 * (20 * 4000);
    const float* __restrict__ p4 = wd4 + (size_t)r0 * (20 * 2000);
    const float* __restrict__ p3 = wd3 + (size_t)r0 * (20 * 1000);
    const float* __restrict__ p2 = wd2 + (size_t)r0 * (20 * 400);
    const float* __restrict__ p1 = wd1 + (size_t)r0 * (20 * 200);
    const float* __restrict__ p0 = wd0 + (size_t)r0 * (20 * 40);
    const float* __restrict__ b6 = wb6 + (size_t)r0 * 8000;
    const float* __restrict__ b5 = wb5 + (size_t)r0 * 4000;
    const float* __restrict__ b4 = wb4 + (size_t)r0 * 2000;
    const float* __restrict__ b3 = wb3 + (size_t)r0 * 1000;
    const float* __restrict__ b2 = wb2 + (size_t)r0 * 400;
    const float* __restrict__ b1 = wb1 + (size_t)r0 * 200;
    const float* __restrict__ b0 = wb0 + (size_t)r0 * 40;

    // ---- P0: stage U (1280 f4 units) + bias (64 units), consume-now ----
#pragma unroll 1
    for (int it = 0; it < 6; it++) {
        const int u = it * 256 + tid;
        if (u >= 1344) break;
        if (u < 1280) {
            const int a = u >> 6, jq = u & 63;
            const int j = base + 4 * jq;
            float4 uu = make_float4(0.f, 0.f, 0.f, 0.f);
            if (j < NFINAL) {
                const float4 v6 = *(const float4*)(p6 + (size_t)a * 8000 + j);
                const float2 v5 = *(const float2*)(p5 + a * 4000 + (j >> 1));
                const float sc = p4[a * 2000 + (j >> 2)] + p3[a * 1000 + (j >> 3)]
                               + p2[a * 400 + j / 20] + p1[a * 200 + j / 40]
                               + p0[a * 40 + j / 200];
                const float c01 = sc + v5.x, c23 = sc + v5.y;
                uu.x = v6.x + c01; uu.y = v6.y + c01;
                uu.z = v6.z + c23; uu.w = v6.w + c23;
            }
            *(float4*)(&U_sh[a * TB + 4 * jq]) = uu;
        } else {
            const int jq = u - 1280;
            const int j = base + 4 * jq;
            float4 uu = make_float4(0.f, 0.f, 0.f, 0.f);
            if (j < NFINAL) {
                const float4 v6 = *(const float4*)(b6 + j);
                const float2 v5 = *(const float2*)(b5 + (j >> 1));
                const float sc = b4[j >> 2] + b3[j >> 3] + b2[j / 20]
                               + b1[j / 40] + b0[j / 200];
                const float c01 = sc + v5.x, c23 = sc + v5.y;
                uu.x = v6.x + c01; uu.y = v6.y + c01;
                uu.z = v6.z + c23; uu.w = v6.w + c23;
            }
            *(float4*)(&bias_sh[4 * jq]) = uu;
        }
    }
    __syncthreads();

    // ---- PA: wave = clusters cb..cb+4 over the whole tile; 2 passes ----
    const int cb = __builtin_amdgcn_readfirstlane(wv * 5);
    const float* __restrict__ cc = compT + cb * 20;   // uniform -> s_load
    const int j = base + 4 * lane;
    const bool ok = j < NFINAL;
    const float4 bi = *(const float4*)(&bias_sh[4 * lane]);

    {   // pass A: clusters cb, cb+1, cb+2
        float4 a0 = bi, a1 = bi, a2 = bi;
#pragma unroll
        for (int a = 0; a < 20; a++) {
            const float4 u = *(const float4*)(&U_sh[a * TB + 4 * lane]);
            const float f0 = cc[a], f1 = cc[20 + a], f2 = cc[40 + a];
            a0.x += f0 * u.x; a0.y += f0 * u.y; a0.z += f0 * u.z; a0.w += f0 * u.w;
            a1.x += f1 * u.x; a1.y += f1 * u.y; a1.z += f1 * u.z; a1.w += f1 * u.w;
            a2.x += f2 * u.x; a2.y += f2 * u.y; a2.z += f2 * u.z; a2.w += f2 * u.w;
        }
        float4 accs[3] = {a0, a1, a2};
#pragma unroll
        for (int k = 0; k < 3; k++) {
            float se = 0.f;
            if (ok) {
                const float4 acc = accs[k];
                union { __hip_bfloat162 h2[2]; uint2 u2; } pk;
                pk.h2[0] = __float22bfloat162_rn(make_float2(acc.x, acc.y));
                pk.h2[1] = __float22bfloat162_rn(make_float2(acc.z, acc.w));
                *(uint2*)(w2 + (size_t)(r * 20 + cb + k) * 8000 + j) = pk.u2;
                // |w| small (~<4): unnormalized exp-sum safe in f32
                se = __expf(acc.x) + __expf(acc.y) + __expf(acc.z) + __expf(acc.w);
            }
#pragma unroll
            for (int off = 32; off > 0; off >>= 1) se += __shfl_down(se, off, 64);
            if (lane == 0) s_part[((size_t)r * NTILE + tile) * 20 + cb + k] = se;
        }
    }
    {   // pass B: clusters cb+3, cb+4
        float4 a0 = bi, a1 = bi;
#pragma unroll
        for (int a = 0; a < 20; a++) {
            const float4 u = *(const float4*)(&U_sh[a * TB + 4 * lane]);
            const float f0 = cc[60 + a], f1 = cc[80 + a];
            a0.x += f0 * u.x; a0.y += f0 * u.y; a0.z += f0 * u.z; a0.w += f0 * u.w;
            a1.x += f1 * u.x; a1.y += f1 * u.y; a1.z += f1 * u.z; a1.w += f1 * u.w;
        }
        float4 accs[2] = {a0, a1};
#pragma unroll
        for (int k = 0; k < 2; k++) {
            float se = 0.f;
            if (ok) {
                const float4 acc = accs[k];
                union { __hip_bfloat162 h2[2]; uint2 u2; } pk;
                pk.h2[0] = __float22bfloat162_rn(make_float2(acc.x, acc.y));
                pk.h2[1] = __float22bfloat162_rn(make_float2(acc.z, acc.w));
                *(uint2*)(w2 + (size_t)(r * 20 + cb + 3 + k) * 8000 + j) = pk.u2;
                se = __expf(acc.x) + __expf(acc.y) + __expf(acc.z) + __expf(acc.w);
            }
#pragma unroll
            for (int off = 32; off > 0; off >>= 1) se += __shfl_down(se, off, 64);
            if (lane == 0) s_part[((size_t)r * NTILE + tile) * 20 + cb + 3 + k] = se;
        }
    }

    // ---- PQ: KL quads for this tile's L6/L5/L4/L3 columns (L2-hot) ----
    float q = 0.f;
#pragma unroll 1
    for (int it = 0; it < 2; it++) {
        const int u = it * 256 + tid;
        if (u >= 480) break;
        const float* P; int K, col;
        if (u < 256)      { P = p6; K = 8000; col = base + u; }
        else if (u < 384) { P = p5; K = 4000; col = (base >> 1) + (u - 256); }
        else if (u < 448) { P = p4; K = 2000; col = (base >> 2) + (u - 384); }
        else              { P = p3; K = 1000; col = (base >> 3) + (u - 448); }
        if (col < K) {
            float x[20];
#pragma unroll
            for (int a = 0; a < 20; a++) x[a] = P[(size_t)a * K + col];
#pragma unroll
            for (int a = 0; a < 20; a++) {
                float t = g2[a * 21] * x[a];          // const offsets -> s_load
#pragma unroll
                for (int b = a + 1; b < 20; b++) t += g2[a * 20 + b] * x[b];
                q += x[a] * t;
            }
        }
    }
#pragma unroll
    for (int off = 32; off > 0; off >>= 1) q += __shfl_down(q, off, 64);
    if (lane == 0) klp[wv] = q;
    __syncthreads();
    if (tid == 0)
        atomicAdd(kl_out, (klp[0] + klp[1] + klp[2] + klp[3]) * (-0.5f / 2.25f));
}

// KL quads for levels 0..2 (40+200+400 = 640 cols per region)
__global__ __launch_bounds__(256, 2) void k_klc(
    const float* __restrict__ g2,
    const float* __restrict__ wd0, const float* __restrict__ wd1,
    const float* __restrict__ wd2,
    const int* __restrict__ regions_oi, float* __restrict__ kl_out)
{
    __shared__ float klp[4];
    const int tid = threadIdx.x;
    const int r0 = regions_oi[blockIdx.x];
    const float* __restrict__ p2 = wd2 + (size_t)r0 * (20 * 400);
    const float* __restrict__ p1 = wd1 + (size_t)r0 * (20 * 200);
    const float* __restrict__ p0 = wd0 + (size_t)r0 * (20 * 40);

    float q = 0.f;
#pragma unroll 1
    for (int it = 0; it < 3; it++) {
        const int u = it * 256 + tid;
        if (u >= 640) break;
        const float* P; int K, col;
        if (u < 400)      { P = p2; K = 400; col = u; }
        else if (u < 600) { P = p1; K = 200; col = u - 400; }
        else              { P = p0; K = 40;  col = u - 600; }
        float x[20];
#pragma unroll
        for (int a = 0; a < 20; a++) x[a] = P[a * K + col];
#pragma unroll
        for (int a = 0; a < 20; a++) {
            float t = g2[a * 21] * x[a];
#pragma unroll
            for (int b = a + 1; b < 20; b++) t += g2[a * 20 + b] * x[b];
            q += x[a] * t;
        }
    }
#pragma unroll
    for (int off = 32; off > 0; off >>= 1) q += __shfl_down(q, off, 64);
    if ((tid & 63) == 0) klp[tid >> 6] = q;
    __syncthreads();
    if (tid == 0)
        atomicAdd(kl_out, (klp[0] + klp[1] + klp[2] + klp[3]) * (-0.5f / 2.25f));
}

__global__ void k_sub(const float* __restrict__ s_part, float* __restrict__ sub)
{
    const int i = blockIdx.x * 256 + threadIdx.x;
    if (i >= NROI * NC) return;
    const int r = i / 20, c = i % 20;
    float s = 0.f;
#pragma unroll 1
    for (int t = 0; t < NTILE; t++) s += s_part[(size_t)(r * NTILE + t) * 20 + c];
    sub[i] = logf(s) + 3.2188758248682006f;   // + log(25)
}

__global__ void k_gather(const int* __restrict__ lri, const int* __restrict__ lci,
                         const int* __restrict__ cli, const int* __restrict__ coords,
                         const __hip_bfloat16* __restrict__ w2,
                         const float* __restrict__ sub,
                         float* __restrict__ out)
{
    const int i = blockIdx.x * 256 + threadIdx.x;
    if (i >= NCUTS) return;
    const int r = lri[i];
    const int c = cli[lci[i]];
    int co = coords[i];
    co = co < 0 ? 0 : (co > 199999 ? 199999 : co);
    const int bin = co / 25;
    const int rc = r * 20 + c;
    out[i] = __bfloat162float(w2[(size_t)rc * 8000 + bin]) - sub[rc];
}

extern "C" void kernel_launch(void* const* d_in, const int* in_sizes, int n_in,
                              void* d_out, int out_size, void* d_ws, size_t ws_size,
                              hipStream_t stream)
{
    const float* comp = (const float*)d_in[0];
    const float* wb[7];
    const float* wd[7];
    if (in_sizes[2] == 400000) {
        for (int l = 0; l < 7; l++) { wb[l] = (const float*)d_in[1 + 2 * l]; wd[l] = (const float*)d_in[2 + 2 * l]; }
    } else {
        for (int l = 0; l < 7; l++) { wb[l] = (const float*)d_in[1 + l]; wd[l] = (const float*)d_in[8 + l]; }
    }
    const int* regions_oi = (const int*)d_in[15];
    const int* lri   = (const int*)d_in[16];
    const int* lci   = (const int*)d_in[17];
    const int* cli   = (const int*)d_in[18];
    const int* coords= (const int*)d_in[19];
    float* out = (float*)d_out;

    __hip_bfloat16* w2 = (__hip_bfloat16*)d_ws;                     // 81.92 MB
    float* s_part = (float*)(w2 + (size_t)NROI * NC * NFINAL);      // 8192*20 f32
    float* sub    = s_part + (size_t)NROI * NTILE * 20;             // 5120 f32
    float* g2buf  = sub + NROI * NC;                                // 400 f32
    float* compT  = g2buf + 400;                                    // 400 f32
    const size_t need = (size_t)NROI * NC * NFINAL * 2
                      + ((size_t)NROI * NTILE * 20 + NROI * NC + 800) * sizeof(float);
    if (ws_size < need) return;

    k_init<<<1, 256, 0, stream>>>(comp, g2buf, compT, out + NCUTS);
    k_main<<<NROI * NTILE, 256, 0, stream>>>(compT, g2buf,
        wb[0], wd[0], wb[1], wd[1], wb[2], wd[2], wb[3], wd[3],
        wb[4], wd[4], wb[5], wd[5], wb[6], wd[6],
        regions_oi, w2, s_part, out + NCUTS);
    k_klc<<<NROI, 256, 0, stream>>>(g2buf, wd[0], wd[1], wd[2],
        regions_oi, out + NCUTS);
    k_sub<<<(NROI * NC + 255) / 256, 256, 0, stream>>>(s_part, sub);
    k_gather<<<(NCUTS + 255) / 256, 256, 0, stream>>>(lri, lci, cli, coords,
        w2, sub, out);
}